// Round 3
// baseline (397.091 us; speedup 1.0000x reference)
//
#include <hip/hip_runtime.h>
#include <math.h>

#define NPART 32768
#define MS 50
#define BLOCK 256

typedef __attribute__((ext_vector_type(8))) short bfrag;   // 8 bf16 (4 VGPRs)
typedef __attribute__((ext_vector_type(4))) float ffrag;   // 4 fp32 (MFMA C/D)

// float -> bf16 bits, round-to-nearest-even (scalar fallback / one-time staging)
__device__ __forceinline__ unsigned short f2bf(float x) {
    unsigned u = __float_as_uint(x);
    u += 0x7fffu + ((u >> 16) & 1u);
    return (unsigned short)(u >> 16);
}

// Packed f32x2 -> bf16x2 in one VALU op on gfx950 (v_cvt_pk_bf16_f32).
#if __has_builtin(__builtin_amdgcn_cvt_pk_bf16_f32)
typedef __attribute__((ext_vector_type(2))) __bf16 bf16x2;
__device__ __forceinline__ unsigned pk2(float a, float b) {
    bf16x2 r = __builtin_amdgcn_cvt_pk_bf16_f32(a, b);   // lo = a, hi = b
    return __builtin_bit_cast(unsigned, r);
}
#else
__device__ __forceinline__ unsigned pk2(float a, float b) {
    return (unsigned)f2bf(a) | ((unsigned)f2bf(b) << 16);
}
#endif

// tanh(x) = 1 - 2/(exp(2x)+1); v_mul+v_exp+v_add+v_rcp+v_sub, saturates at inf.
__device__ __forceinline__ float fast_tanh(float x) {
    float e = __expf(2.0f * x);
    return 1.0f - __fdividef(2.0f, e + 1.0f);
}

// One wave = 16 particles. Lane l: p = l&15 (particle col), q = l>>4 (quad).
// Lane owns X dims [8q, 8q+8) of particle p == B-operand layout of
// mfma_f32_16x16x32_bf16. Weights in registers as A-fragments.
// C-layout -> B-layout fixups for H and Z via WAVE-PRIVATE LDS round trips:
// no __syncthreads needed (per-wave DS ordering); wave_barrier() is a free
// compiler fence.
__global__ __launch_bounds__(BLOCK, 2)
void fused_sde_mfma(const float* __restrict__ obs,
                    const float* __restrict__ x0,
                    const float* __restrict__ v0,
                    const float* __restrict__ noise,
                    const float* __restrict__ gW1,
                    const float* __restrict__ gb1,
                    const float* __restrict__ gW2,
                    const float* __restrict__ gb2,
                    const float* __restrict__ gtheta,
                    const int* __restrict__ gobs_idx,
                    const int* __restrict__ gctrl,
                    float* __restrict__ outX,
                    float* __restrict__ outV)
{
    // H row = 136 bf16 (272 B), Z row = 36 fp32 (144 B): padded, 16B aligned.
    __shared__ __align__(16) unsigned short Hlds[4][16][136];
    __shared__ __align__(16) float Zlds[4][16][36];

    const int tid  = threadIdx.x;
    const int w    = tid >> 6;
    const int lane = tid & 63;
    const int p    = lane & 15;
    const int q    = lane >> 4;

    const int part = blockIdx.x * 64 + w * 16 + p;

    // ---- weights into register A-fragments (one-time) ----
    bfrag A1[8][2];
    #pragma unroll
    for (int mt = 0; mt < 8; ++mt) {
        const int h = 16 * mt + p;
        #pragma unroll
        for (int kt = 0; kt < 2; ++kt) {
            bfrag a;
            #pragma unroll
            for (int j = 0; j < 8; ++j) {
                const int f = 32 * kt + 8 * q + j;
                const float wv = (f < 42) ? gW1[f * 128 + h] : 0.0f;
                a[j] = (short)f2bf(wv);
            }
            A1[mt][kt] = a;
        }
    }
    bfrag A2[2][4];
    #pragma unroll
    for (int mt = 0; mt < 2; ++mt) {
        const int d = 16 * mt + p;
        #pragma unroll
        for (int kt = 0; kt < 4; ++kt) {
            bfrag a;
            #pragma unroll
            for (int j = 0; j < 8; ++j)
                a[j] = (short)f2bf(gW2[(32 * kt + 8 * q + j) * 32 + d]);
            A2[mt][kt] = a;
        }
    }

    // ---- biases into registers (C-layout: lane (p,q) holds rows 4q+r) ----
    ffrag Bia1[8];
    #pragma unroll
    for (int mt = 0; mt < 8; ++mt) {
        float4 b = *(const float4*)(gb1 + 16 * mt + 4 * q);
        Bia1[mt] = ffrag{b.x, b.y, b.z, b.w};
    }
    ffrag Bia2a, Bia2b;
    {
        float4 b = *(const float4*)(gb2 + 4 * q);
        Bia2a = ffrag{b.x, b.y, b.z, b.w};
        float4 c = *(const float4*)(gb2 + 16 + 4 * q);
        Bia2b = ffrag{c.x, c.y, c.z, c.w};
    }

    const float theta = gtheta[0];
    const float tfeat = (float)gobs_idx[0];
    const float cr    = (float)gctrl[0];
    const float dt      = 1.0f / (float)MS;
    const float sqrt_dt = sqrtf(dt);
    const float ax  = 1.0f - dt * theta;     // X multiplier
    const float bcr = dt * cr;               // Z multiplier (negated in fma)
    const float kv  = dt * (0.5f - cr);      // V drift multiplier

    // K-tile-1 B fragment: q0 = Y[0..7], q1 = [s, tfeat, 0...], q2/q3 = 0.
    bfrag BY = {0, 0, 0, 0, 0, 0, 0, 0};
    if (q == 0) {
        #pragma unroll
        for (int j = 0; j < 8; ++j) BY[j] = (short)f2bf(obs[j]);
    } else if (q == 1) {
        BY[1] = (short)f2bf(tfeat);
    }

    // ---- per-lane state ----
    float X[8];
    {
        const float4* xp = (const float4*)(x0 + (size_t)part * 32 + 8 * q);
        float4 a = xp[0], b = xp[1];
        X[0] = a.x; X[1] = a.y; X[2] = a.z; X[3] = a.w;
        X[4] = b.x; X[5] = b.y; X[6] = b.z; X[7] = b.w;
    }
    float V = v0[part];

    const float* nbase = noise + (size_t)part * 32 + 8 * q;
    float4 nc0 = ((const float4*)nbase)[0];
    float4 nc1 = ((const float4*)nbase)[1];

    unsigned short* hrow = &Hlds[w][p][0];
    float*          zrow = &Zlds[w][p][0];

    #pragma unroll 1
    for (int m = 0; m < MS; ++m) {
        const int mn = (m + 1 < MS) ? m + 1 : m;
        const float* np = nbase + (size_t)mn * ((size_t)NPART * 32);
        float4 nn0 = ((const float4*)np)[0];
        float4 nn1 = ((const float4*)np)[1];

        // B fragment K-tile 0: X -> packed bf16 (4 v_cvt_pk ops)
        int4 bxw = make_int4((int)pk2(X[0], X[1]), (int)pk2(X[2], X[3]),
                             (int)pk2(X[4], X[5]), (int)pk2(X[6], X[7]));
        bfrag BX = __builtin_bit_cast(bfrag, bxw);

        bfrag B1 = BY;
        if (q == 1) B1[0] = (short)f2bf((float)m * dt);

        // ---- GEMM1 + bias + tanh + pack to LDS (wave-private) ----
        #pragma unroll
        for (int mt = 0; mt < 8; ++mt) {
            ffrag c = Bia1[mt];
            c = __builtin_amdgcn_mfma_f32_16x16x32_bf16(A1[mt][0], BX, c, 0, 0, 0);
            c = __builtin_amdgcn_mfma_f32_16x16x32_bf16(A1[mt][1], B1, c, 0, 0, 0);
            const unsigned u0 = pk2(fast_tanh(c[0]), fast_tanh(c[1]));
            const unsigned u1 = pk2(fast_tanh(c[2]), fast_tanh(c[3]));
            *(uint2*)&hrow[16 * mt + 4 * q] = make_uint2(u0, u1);
        }

        __builtin_amdgcn_wave_barrier();   // compiler fence; DS in-order per wave

        // ---- GEMM2 ----
        ffrag C2_0 = Bia2a;
        ffrag C2_1 = Bia2b;
        #pragma unroll
        for (int kt = 0; kt < 4; ++kt) {
            bfrag B2 = *(const bfrag*)&hrow[32 * kt + 8 * q];
            C2_0 = __builtin_amdgcn_mfma_f32_16x16x32_bf16(A2[0][kt], B2, C2_0, 0, 0, 0);
            C2_1 = __builtin_amdgcn_mfma_f32_16x16x32_bf16(A2[1][kt], B2, C2_1, 0, 0, 0);
        }

        // Z: C-layout -> LDS -> B-layout (wave-private)
        *(ffrag*)&zrow[4 * q]      = C2_0;
        *(ffrag*)&zrow[16 + 4 * q] = C2_1;

        __builtin_amdgcn_wave_barrier();

        float4 z0 = *(const float4*)&zrow[8 * q];
        float4 z1 = *(const float4*)&zrow[8 * q + 4];
        float Z[8] = {z0.x, z0.y, z0.z, z0.w, z1.x, z1.y, z1.z, z1.w};
        float Nn[8] = {nc0.x, nc0.y, nc0.z, nc0.w, nc1.x, nc1.y, nc1.z, nc1.w};

        // V drift: (0.5 - cr)*dt*sum(Z^2) + sqrt_dt*sum(Z*n)
        float s2 = 0.0f, sn = 0.0f;
        #pragma unroll
        for (int j = 0; j < 8; ++j) {
            s2 = fmaf(Z[j], Z[j], s2);
            sn = fmaf(Z[j], Nn[j], sn);
        }
        s2 += __shfl_xor(s2, 16); s2 += __shfl_xor(s2, 32);
        sn += __shfl_xor(sn, 16); sn += __shfl_xor(sn, 32);
        V = fmaf(kv, s2, fmaf(sqrt_dt, sn, V));

        // X = ax*X - bcr*Z + sqrt_dt*n
        #pragma unroll
        for (int j = 0; j < 8; ++j) {
            float t = fmaf(-bcr, Z[j], sqrt_dt * Nn[j]);
            X[j] = fmaf(ax, X[j], t);
        }

        nc0 = nn0; nc1 = nn1;
    }

    float4* xout = (float4*)(outX + (size_t)part * 32 + 8 * q);
    xout[0] = make_float4(X[0], X[1], X[2], X[3]);
    xout[1] = make_float4(X[4], X[5], X[6], X[7]);
    if (q == 0) outV[part] = V;
}

extern "C" void kernel_launch(void* const* d_in, const int* in_sizes, int n_in,
                              void* d_out, int out_size, void* d_ws, size_t ws_size,
                              hipStream_t stream) {
    const float* obs   = (const float*)d_in[0];
    const float* x0    = (const float*)d_in[1];
    const float* v0    = (const float*)d_in[2];
    const float* noise = (const float*)d_in[3];
    const float* W1    = (const float*)d_in[4];
    const float* b1    = (const float*)d_in[5];
    const float* W2    = (const float*)d_in[6];
    const float* b2    = (const float*)d_in[7];
    const float* th    = (const float*)d_in[8];
    const int*   oi    = (const int*)d_in[9];
    const int*   cr    = (const int*)d_in[10];

    float* outX = (float*)d_out;
    float* outV = outX + (size_t)NPART * 32;

    dim3 grid(NPART / 64);   // 512 blocks x 4 waves x 16 particles
    fused_sde_mfma<<<grid, BLOCK, 0, stream>>>(obs, x0, v0, noise, W1, b1, W2, b2,
                                               th, oi, cr, outX, outV);
}